// Round 15
// baseline (205.999 us; speedup 1.0000x reference)
//
#include <hip/hip_runtime.h>
#include <hip/hip_fp16.h>

#define DD 4096
#define NROWS 16384
#define EPS 1e-6f
#define RPB 8   // rows per block (persistent ring)

typedef float fx4 __attribute__((ext_vector_type(4)));
typedef int   ix4 __attribute__((ext_vector_type(4)));

// ws: +0 float gmax, +256 float rowmax[16384]. q8 intermediate lives in
// d_out (r14 layout): row r dword 4t+i <-> fx4 slot t+256i, t in [0,256).
//
// pass1_pc: WAVE-SPECIALIZED producer/consumer. Waves 0-1 (tid<128) only
// LOAD (their vmcnt never contains a store); waves 2-3 only STORE. p is
// handed off through a double-buffered LDS ring; one barrier per row-step.
__global__ __launch_bounds__(256) void pass1_pc(
    const float* __restrict__ x, const float* __restrict__ res,
    const float* __restrict__ gamma, unsigned int* __restrict__ outw,
    float* __restrict__ rowmax) {
  __shared__ unsigned long long ph[2][1024];  // fp16x4 per fx4 slot, 8KB/buf
  __shared__ float s_ss[2][2], s_mx[2][2];

  const int tid = threadIdx.x;
  const int base_row = blockIdx.x * RPB;

  for (int k = 0; k <= RPB; ++k) {
    if (tid < 128) {  // ---- producer waves 0-1 ----
      if (k < RPB) {
        const int row = base_row + k;
        const fx4* x4 = (const fx4*)(x + (size_t)row * DD);
        const fx4* r4 = (const fx4*)(res + (size_t)row * DD);
        const fx4* g4 = (const fx4*)gamma;
        unsigned long long* buf = ph[k & 1];
        float ss = 0.f, mx = 0.f;
#pragma unroll
        for (int i = 0; i < 8; ++i) {
          const int s = tid + i * 128;  // coalesced 1KB/wave/instr
          fx4 y = x4[s] + r4[s];
          ss += y.x * y.x + y.y * y.y + y.z * y.z + y.w * y.w;
          fx4 p = y * g4[s];
          mx = fmaxf(mx, fmaxf(fmaxf(fabsf(p.x), fabsf(p.y)),
                               fmaxf(fabsf(p.z), fabsf(p.w))));
          union { unsigned long long u; __half2 h2[2]; } pk_;
          pk_.h2[0] = __floats2half2_rn(p.x, p.y);
          pk_.h2[1] = __floats2half2_rn(p.z, p.w);
          buf[s] = pk_.u;
        }
#pragma unroll
        for (int off = 32; off > 0; off >>= 1) {
          ss += __shfl_down(ss, off, 64);
          mx = fmaxf(mx, __shfl_down(mx, off, 64));
        }
        if ((tid & 63) == 0) {
          s_ss[k & 1][tid >> 6] = ss;
          s_mx[k & 1][tid >> 6] = mx;
        }
      }
    } else {          // ---- consumer waves 2-3 ----
      if (k > 0) {
        const int row = base_row + k - 1;
        const int c = tid - 128;          // 0..127
        const int pb = (k - 1) & 1;
        const float tss = s_ss[pb][0] + s_ss[pb][1];
        const float tmx = fmaxf(s_mx[pb][0], s_mx[pb][1]);
        const float rs = rsqrtf(tss * (1.0f / DD) + EPS);
        if (c == 0) rowmax[row] = tmx * rs;
        const float inv = tmx > 0.f ? 127.0f / tmx : 0.f;
        const unsigned long long* buf = ph[pb];
        unsigned int dw[8];
#pragma unroll
        for (int j = 0; j < 8; ++j) {
          union { unsigned long long u; __half2 h2[2]; } v;
          v.u = buf[c + j * 128];
          float2 f0 = __half22float2(v.h2[0]);
          float2 f1 = __half22float2(v.h2[1]);
          int a = min(max(__float2int_rn(f0.x * inv), -127), 127);
          int b = min(max(__float2int_rn(f0.y * inv), -127), 127);
          int d = min(max(__float2int_rn(f1.x * inv), -127), 127);
          int e = min(max(__float2int_rn(f1.y * inv), -127), 127);
          dw[j] = (unsigned)(a & 255) | ((unsigned)(b & 255) << 8) |
                  ((unsigned)(d & 255) << 16) | ((unsigned)(e & 255) << 24);
        }
        // r14 q8 layout: dword 4t+i <-> slot t+256i.
        // q0 @ dword 4c (t=c): slots c+256i = j even. q1 @ 4c+512 (t=c+128).
        ix4 q0, q1;
        ((int*)&q0)[0] = dw[0]; ((int*)&q0)[1] = dw[2];
        ((int*)&q0)[2] = dw[4]; ((int*)&q0)[3] = dw[6];
        ((int*)&q1)[0] = dw[1]; ((int*)&q1)[1] = dw[3];
        ((int*)&q1)[2] = dw[5]; ((int*)&q1)[3] = dw[7];
        unsigned int* qrow = outw + (size_t)row * DD;
        *(ix4*)(qrow + 4 * c) = q0;
        *(ix4*)(qrow + 4 * c + 512) = q1;
      }
    }
    __syncthreads();  // all waves rendezvous once per row-step
  }
}

__global__ __launch_bounds__(1024) void reduce_gmax(
    const float* __restrict__ rowmax, float* __restrict__ gmax) {
  const int t = threadIdx.x;
  float m = 0.f;
#pragma unroll
  for (int i = 0; i < NROWS / 1024; ++i) m = fmaxf(m, rowmax[t + i * 1024]);
#pragma unroll
  for (int off = 32; off > 0; off >>= 1) m = fmaxf(m, __shfl_down(m, off, 64));
  __shared__ float s[16];
  if ((t & 63) == 0) s[t >> 6] = m;
  __syncthreads();
  if (t == 0) {
    float r = s[0];
#pragma unroll
    for (int i = 1; i < 16; ++i) r = fmaxf(r, s[i]);
    *gmax = r;
  }
}

// Pass 2 (r14's, race-free in-place): thread t reads its own ix4 at dword
// 4t (slots t+256i), rescales by rowmax/gmax, overwrites its row span.
__global__ __launch_bounds__(256) void pass2(
    unsigned int* __restrict__ outw, const float* __restrict__ rowmax,
    const float* __restrict__ gmax, int* __restrict__ out) {
  const int row = blockIdx.x;
  const int t = threadIdx.x;
  const float c = rowmax[row] / *gmax;  // <= 1
  union { ix4 v; unsigned int w[4]; } u;
  u.v = *(const ix4*)(outw + (size_t)row * DD + 4 * t);
  ix4* orow = (ix4*)(out + (size_t)row * DD);
#pragma unroll
  for (int i = 0; i < 4; ++i) {
    const unsigned int w = u.w[i];
    ix4 q;
    q.x = min(max(__float2int_rn((float)((int)(w << 24) >> 24) * c), -128), 127);
    q.y = min(max(__float2int_rn((float)((int)(w << 16) >> 24) * c), -128), 127);
    q.z = min(max(__float2int_rn((float)((int)(w << 8) >> 24) * c), -128), 127);
    q.w = min(max(__float2int_rn((float)((int)w >> 24) * c), -128), 127);
    orow[t + i * 256] = q;  // i=0 exactly covers the dwords read
  }
}

// ---- Fallback (ws < 2 MB): recompute path ----
__global__ __launch_bounds__(256) void pass1_nb(
    const float* __restrict__ x, const float* __restrict__ res,
    const float* __restrict__ gamma, float* __restrict__ rstd,
    float* __restrict__ rowmax) {
  const int row = blockIdx.x;
  const int t = threadIdx.x;
  const fx4* x4 = (const fx4*)(x + (size_t)row * DD);
  const fx4* r4 = (const fx4*)(res + (size_t)row * DD);
  const fx4* g4 = (const fx4*)gamma;
  float ss = 0.f, mx = 0.f;
#pragma unroll
  for (int i = 0; i < 4; ++i) {
    const int idx = t + i * 256;
    fx4 y = x4[idx] + r4[idx];
    ss += y.x * y.x + y.y * y.y + y.z * y.z + y.w * y.w;
    fx4 p = y * g4[idx];
    mx = fmaxf(mx, fmaxf(fmaxf(fabsf(p.x), fabsf(p.y)),
                         fmaxf(fabsf(p.z), fabsf(p.w))));
  }
#pragma unroll
  for (int off = 32; off > 0; off >>= 1) {
    ss += __shfl_down(ss, off, 64);
    mx = fmaxf(mx, __shfl_down(mx, off, 64));
  }
  __shared__ float s_ss[4], s_mx[4];
  const int wave = t >> 6, lane = t & 63;
  if (lane == 0) { s_ss[wave] = ss; s_mx[wave] = mx; }
  __syncthreads();
  if (t == 0) {
    float tss = s_ss[0] + s_ss[1] + s_ss[2] + s_ss[3];
    float tmx = fmaxf(fmaxf(s_mx[0], s_mx[1]), fmaxf(s_mx[2], s_mx[3]));
    float rs = rsqrtf(tss * (1.0f / DD) + EPS);
    rstd[row] = rs;
    rowmax[row] = tmx * rs;
  }
}

__global__ __launch_bounds__(256) void pass2_nb(
    const float* __restrict__ x, const float* __restrict__ res,
    const float* __restrict__ gamma, const float* __restrict__ rstd,
    const float* __restrict__ gmax, int* __restrict__ out) {
  const int row = blockIdx.x;
  const int t = threadIdx.x;
  const float c = rstd[row] * (127.0f / *gmax);
  const fx4* x4 = (const fx4*)(x + (size_t)row * DD);
  const fx4* r4 = (const fx4*)(res + (size_t)row * DD);
  const fx4* g4 = (const fx4*)gamma;
  ix4* o4 = (ix4*)(out + (size_t)row * DD);
#pragma unroll
  for (int i = 0; i < 4; ++i) {
    const int idx = t + i * 256;
    fx4 xv = x4[idx], rv = r4[idx], gv = g4[idx];
    ix4 q;
    q.x = min(max(__float2int_rn((xv.x + rv.x) * gv.x * c), -128), 127);
    q.y = min(max(__float2int_rn((xv.y + rv.y) * gv.y * c), -128), 127);
    q.z = min(max(__float2int_rn((xv.z + rv.z) * gv.z * c), -128), 127);
    q.w = min(max(__float2int_rn((xv.w + rv.w) * gv.w * c), -128), 127);
    o4[idx] = q;
  }
}

extern "C" void kernel_launch(void* const* d_in, const int* in_sizes, int n_in,
                              void* d_out, int out_size, void* d_ws, size_t ws_size,
                              hipStream_t stream) {
  const float* x     = (const float*)d_in[0];
  const float* res   = (const float*)d_in[1];
  const float* gamma = (const float*)d_in[2];
  int* out = (int*)d_out;

  char* ws = (char*)d_ws;
  float* gmax   = (float*)ws;
  float* rowmax = (float*)(ws + 256);
  float* rstd   = (float*)(ws + 256 + 64 * 1024);  // fallback only

  if (ws_size >= (size_t)(2 << 20)) {
    unsigned int* outw = (unsigned int*)d_out;
    pass1_pc<<<NROWS / RPB, 256, 0, stream>>>(x, res, gamma, outw, rowmax);
    reduce_gmax<<<1, 1024, 0, stream>>>(rowmax, gmax);
    pass2<<<NROWS, 256, 0, stream>>>(outw, rowmax, gmax, out);
  } else {
    pass1_nb<<<NROWS, 256, 0, stream>>>(x, res, gamma, rstd, rowmax);
    reduce_gmax<<<1, 1024, 0, stream>>>(rowmax, gmax);
    pass2_nb<<<NROWS, 256, 0, stream>>>(x, res, gamma, rstd, gmax, out);
  }
}

// Round 16
// 194.360 us; speedup vs baseline: 1.0599x; 1.0599x over previous
//
#include <hip/hip_runtime.h>

#define DD 4096
#define NROWS 16384
#define EPS 1e-6f

typedef float fx4 __attribute__((ext_vector_type(4)));
typedef int   ix4 __attribute__((ext_vector_type(4)));

// ws: +0 float gmax, +256 float rowmax[16384].
// q8 intermediate lives in d_out (r14 layout): row r's packed int8 occupies
// dwords [4096r, 4096r+1024); dword 4t+i <-> fx4 slot t+256i, t in [0,256).

// pass1_pw: PERSISTENT WAVES, no barrier, no LDS, no block retire between
// rows. 2048 waves x 8 rows. Wave w, row-iteration k -> row w + 2048k
// (concurrent waves sweep a contiguous 32MB window). Per row: coalesced
// 1KB wave-loads, p kept in regs, butterfly reduce, 4x coalesced 16B q8
// stores, then straight into the next row's loads (stores drain in their
// shadow -- the untested cell: bulk store WITHOUT retire/barrier after it).
__global__ __launch_bounds__(256) void pass1_pw(
    const float* __restrict__ x, const float* __restrict__ res,
    const float* __restrict__ gamma, unsigned int* __restrict__ outw,
    float* __restrict__ rowmax) {
  const int wid = (int)(blockIdx.x << 2) | ((int)threadIdx.x >> 6);  // 0..2047
  const int l = threadIdx.x & 63;
  const fx4* g4 = (const fx4*)gamma;

  for (int k = 0; k < 8; ++k) {
    const int row = wid + (k << 11);
    const fx4* x4 = (const fx4*)(x + (size_t)row * DD);
    const fx4* r4 = (const fx4*)(res + (size_t)row * DD);

    fx4 p[4][4];
    float ss = 0.f, mx = 0.f;
#pragma unroll
    for (int s = 0; s < 4; ++s) {
#pragma unroll
      for (int i = 0; i < 4; ++i) {
        const int a = 64 * s + l + 256 * i;  // lane-stride 16B: coalesced
        fx4 y = x4[a] + r4[a];
        ss += y.x * y.x + y.y * y.y + y.z * y.z + y.w * y.w;
        fx4 pv = y * g4[a];
        p[s][i] = pv;
        mx = fmaxf(mx, fmaxf(fmaxf(fabsf(pv.x), fabsf(pv.y)),
                             fmaxf(fabsf(pv.z), fabsf(pv.w))));
      }
    }
    // butterfly: ALL lanes end with row totals (no LDS, no barrier)
#pragma unroll
    for (int off = 1; off < 64; off <<= 1) {
      ss += __shfl_xor(ss, off, 64);
      mx = fmaxf(mx, __shfl_xor(mx, off, 64));
    }
    const float rs = rsqrtf(ss * (1.0f / DD) + EPS);
    if (l == 0) rowmax[row] = mx * rs;
    const float inv = mx > 0.f ? 127.0f / mx : 0.f;

    unsigned int* qrow = outw + (size_t)row * DD;
#pragma unroll
    for (int s = 0; s < 4; ++s) {
      ix4 d;
      int* dp = (int*)&d;
#pragma unroll
      for (int i = 0; i < 4; ++i) {
        int a0 = min(max(__float2int_rn(p[s][i].x * inv), -127), 127);
        int b0 = min(max(__float2int_rn(p[s][i].y * inv), -127), 127);
        int c0 = min(max(__float2int_rn(p[s][i].z * inv), -127), 127);
        int e0 = min(max(__float2int_rn(p[s][i].w * inv), -127), 127);
        dp[i] = (a0 & 255) | ((b0 & 255) << 8) | ((c0 & 255) << 16) |
                ((e0 & 255) << 24);
      }
      // t = 64s + l: dwords [4t,4t+4) in row's q8 slot; lane-stride 16B
      *(ix4*)(qrow + 4 * (64 * s + l)) = d;
    }
    // no barrier, no retire: next row's loads issue behind these stores
  }
}

__global__ __launch_bounds__(1024) void reduce_gmax(
    const float* __restrict__ rowmax, float* __restrict__ gmax) {
  const int t = threadIdx.x;
  float m = 0.f;
#pragma unroll
  for (int i = 0; i < NROWS / 1024; ++i) m = fmaxf(m, rowmax[t + i * 1024]);
#pragma unroll
  for (int off = 32; off > 0; off >>= 1) m = fmaxf(m, __shfl_down(m, off, 64));
  __shared__ float s[16];
  if ((t & 63) == 0) s[t >> 6] = m;
  __syncthreads();
  if (t == 0) {
    float r = s[0];
#pragma unroll
    for (int i = 1; i < 16; ++i) r = fmaxf(r, s[i]);
    *gmax = r;
  }
}

// Pass 2 (r14's, proven): thread t reads its own ix4 at dword 4t (fx4 slots
// t+256i), rescales by rowmax/gmax, overwrites its row span; i=0 exactly
// covers the dwords read (per-thread RAW only -> race-free in-place).
__global__ __launch_bounds__(256) void pass2(
    unsigned int* __restrict__ outw, const float* __restrict__ rowmax,
    const float* __restrict__ gmax, int* __restrict__ out) {
  const int row = blockIdx.x;
  const int t = threadIdx.x;
  const float c = rowmax[row] / *gmax;  // <= 1
  union { ix4 v; unsigned int w[4]; } u;
  u.v = *(const ix4*)(outw + (size_t)row * DD + 4 * t);
  ix4* orow = (ix4*)(out + (size_t)row * DD);
#pragma unroll
  for (int i = 0; i < 4; ++i) {
    const unsigned int w = u.w[i];
    ix4 q;
    q.x = min(max(__float2int_rn((float)((int)(w << 24) >> 24) * c), -128), 127);
    q.y = min(max(__float2int_rn((float)((int)(w << 16) >> 24) * c), -128), 127);
    q.z = min(max(__float2int_rn((float)((int)(w << 8) >> 24) * c), -128), 127);
    q.w = min(max(__float2int_rn((float)((int)w >> 24) * c), -128), 127);
    orow[t + i * 256] = q;
  }
}

// ---- Fallback (ws < 2 MB): recompute path ----
__global__ __launch_bounds__(256) void pass1_nb(
    const float* __restrict__ x, const float* __restrict__ res,
    const float* __restrict__ gamma, float* __restrict__ rstd,
    float* __restrict__ rowmax) {
  const int row = blockIdx.x;
  const int t = threadIdx.x;
  const fx4* x4 = (const fx4*)(x + (size_t)row * DD);
  const fx4* r4 = (const fx4*)(res + (size_t)row * DD);
  const fx4* g4 = (const fx4*)gamma;
  float ss = 0.f, mx = 0.f;
#pragma unroll
  for (int i = 0; i < 4; ++i) {
    const int idx = t + i * 256;
    fx4 y = x4[idx] + r4[idx];
    ss += y.x * y.x + y.y * y.y + y.z * y.z + y.w * y.w;
    fx4 p = y * g4[idx];
    mx = fmaxf(mx, fmaxf(fmaxf(fabsf(p.x), fabsf(p.y)),
                         fmaxf(fabsf(p.z), fabsf(p.w))));
  }
#pragma unroll
  for (int off = 32; off > 0; off >>= 1) {
    ss += __shfl_down(ss, off, 64);
    mx = fmaxf(mx, __shfl_down(mx, off, 64));
  }
  __shared__ float s_ss[4], s_mx[4];
  const int wave = t >> 6, lane = t & 63;
  if (lane == 0) { s_ss[wave] = ss; s_mx[wave] = mx; }
  __syncthreads();
  if (t == 0) {
    float tss = s_ss[0] + s_ss[1] + s_ss[2] + s_ss[3];
    float tmx = fmaxf(fmaxf(s_mx[0], s_mx[1]), fmaxf(s_mx[2], s_mx[3]));
    float rs = rsqrtf(tss * (1.0f / DD) + EPS);
    rstd[row] = rs;
    rowmax[row] = tmx * rs;
  }
}

__global__ __launch_bounds__(256) void pass2_nb(
    const float* __restrict__ x, const float* __restrict__ res,
    const float* __restrict__ gamma, const float* __restrict__ rstd,
    const float* __restrict__ gmax, int* __restrict__ out) {
  const int row = blockIdx.x;
  const int t = threadIdx.x;
  const float c = rstd[row] * (127.0f / *gmax);
  const fx4* x4 = (const fx4*)(x + (size_t)row * DD);
  const fx4* r4 = (const fx4*)(res + (size_t)row * DD);
  const fx4* g4 = (const fx4*)gamma;
  ix4* o4 = (ix4*)(out + (size_t)row * DD);
#pragma unroll
  for (int i = 0; i < 4; ++i) {
    const int idx = t + i * 256;
    fx4 xv = x4[idx], rv = r4[idx], gv = g4[idx];
    ix4 q;
    q.x = min(max(__float2int_rn((xv.x + rv.x) * gv.x * c), -128), 127);
    q.y = min(max(__float2int_rn((xv.y + rv.y) * gv.y * c), -128), 127);
    q.z = min(max(__float2int_rn((xv.z + rv.z) * gv.z * c), -128), 127);
    q.w = min(max(__float2int_rn((xv.w + rv.w) * gv.w * c), -128), 127);
    o4[idx] = q;
  }
}

extern "C" void kernel_launch(void* const* d_in, const int* in_sizes, int n_in,
                              void* d_out, int out_size, void* d_ws, size_t ws_size,
                              hipStream_t stream) {
  const float* x     = (const float*)d_in[0];
  const float* res   = (const float*)d_in[1];
  const float* gamma = (const float*)d_in[2];
  int* out = (int*)d_out;

  char* ws = (char*)d_ws;
  float* gmax   = (float*)ws;
  float* rowmax = (float*)(ws + 256);
  float* rstd   = (float*)(ws + 256 + 64 * 1024);  // fallback only

  if (ws_size >= (size_t)(2 << 20)) {
    unsigned int* outw = (unsigned int*)d_out;
    pass1_pw<<<512, 256, 0, stream>>>(x, res, gamma, outw, rowmax);
    reduce_gmax<<<1, 1024, 0, stream>>>(rowmax, gmax);
    pass2<<<NROWS, 256, 0, stream>>>(outw, rowmax, gmax, out);
  } else {
    pass1_nb<<<NROWS, 256, 0, stream>>>(x, res, gamma, rstd, rowmax);
    reduce_gmax<<<1, 1024, 0, stream>>>(rowmax, gmax);
    pass2_nb<<<NROWS, 256, 0, stream>>>(x, res, gamma, rstd, gmax, out);
  }
}

// Round 17
// 190.559 us; speedup vs baseline: 1.0810x; 1.0199x over previous
//
#include <hip/hip_runtime.h>

#define DD 4096
#define NROWS 16384
#define EPS 1e-6f

typedef float fx4 __attribute__((ext_vector_type(4)));
typedef int   ix4 __attribute__((ext_vector_type(4)));

// ws: +0 float gmax, +256 float rowmax[16384].
// q8 intermediate in d_out (r14 layout): row r dwords [4096r,4096r+1024);
// dword 4t+i <-> fx4 slot t+256i.

__device__ __forceinline__ void gload_lds16(const void* g, void* l) {
  // async 16B global->LDS; dest = wave-uniform base + lane*16 (implicit)
  __builtin_amdgcn_global_load_lds(
      (const __attribute__((address_space(1))) void*)g,
      (__attribute__((address_space(3))) void*)l, 16, 0, 0);
}

// Pass 1: block-per-row. Issue the ENTIRE 32KB row (x+res) as 8 async
// global_load_lds wave-instructions (no VGPR dest -> compiler cannot
// shallow-batch it), drain once at the barrier, then compute from LDS,
// reduce, quantize vs row max, store q8 into d_out (r14 layout).
__global__ __launch_bounds__(256) void pass1_lds(
    const float* __restrict__ x, const float* __restrict__ res,
    const float* __restrict__ gamma, unsigned int* __restrict__ outw,
    float* __restrict__ rowmax) {
  __shared__ float xl[DD];            // 16 KB
  __shared__ float rl[DD];            // 16 KB
  __shared__ float s_ss[4], s_mx[4];

  const int t = threadIdx.x;
  const int w = t >> 6, l = t & 63;
  const int row = blockIdx.x;
  const char* xb = (const char*)(x + (size_t)row * DD);
  const char* rb = (const char*)(res + (size_t)row * DD);

  // 8 x 16B async loads per thread-slot: wave w, instr i stages bytes
  // [(4w+i)*1024, +1024) of each stream; LDS fill is linear (xl[j]=x[j]).
#pragma unroll
  for (int i = 0; i < 4; ++i) {
    const int off = ((w << 2) | i) << 10;  // wave-uniform byte offset
    gload_lds16(xb + off + l * 16, (char*)xl + off);
    gload_lds16(rb + off + l * 16, (char*)rl + off);
  }
  __syncthreads();  // single vmcnt drain + barrier; 32KB was in flight

  const fx4* g4  = (const fx4*)gamma;
  const fx4* xlv = (const fx4*)xl;
  const fx4* rlv = (const fx4*)rl;

  fx4 p[4];
  float ss = 0.f, mx = 0.f;
#pragma unroll
  for (int i = 0; i < 4; ++i) {
    const int idx = t + i * 256;            // standard b128 LDS pattern
    fx4 y = xlv[idx] + rlv[idx];
    ss += y.x * y.x + y.y * y.y + y.z * y.z + y.w * y.w;
    p[i] = y * g4[idx];
    mx = fmaxf(mx, fmaxf(fmaxf(fabsf(p[i].x), fabsf(p[i].y)),
                         fmaxf(fabsf(p[i].z), fabsf(p[i].w))));
  }
#pragma unroll
  for (int off = 32; off > 0; off >>= 1) {
    ss += __shfl_down(ss, off, 64);
    mx = fmaxf(mx, __shfl_down(mx, off, 64));
  }
  if (l == 0) { s_ss[w] = ss; s_mx[w] = mx; }
  __syncthreads();
  const float tss = s_ss[0] + s_ss[1] + s_ss[2] + s_ss[3];
  const float tmx = fmaxf(fmaxf(s_mx[0], s_mx[1]), fmaxf(s_mx[2], s_mx[3]));
  const float rs = rsqrtf(tss * (1.0f / DD) + EPS);
  if (t == 0) rowmax[row] = tmx * rs;        // normalized row max
  const float inv = tmx > 0.f ? 127.0f / tmx : 0.f;

  ix4 d;
  int* dp = (int*)&d;
#pragma unroll
  for (int i = 0; i < 4; ++i) {
    int a = min(max(__float2int_rn(p[i].x * inv), -127), 127);
    int b = min(max(__float2int_rn(p[i].y * inv), -127), 127);
    int c = min(max(__float2int_rn(p[i].z * inv), -127), 127);
    int e = min(max(__float2int_rn(p[i].w * inv), -127), 127);
    dp[i] = (a & 255) | ((b & 255) << 8) | ((c & 255) << 16) | ((e & 255) << 24);
  }
  *(ix4*)(outw + (size_t)row * DD + 4 * t) = d;  // coalesced 16B q8 store
}

__global__ __launch_bounds__(1024) void reduce_gmax(
    const float* __restrict__ rowmax, float* __restrict__ gmax) {
  const int t = threadIdx.x;
  float m = 0.f;
#pragma unroll
  for (int i = 0; i < NROWS / 1024; ++i) m = fmaxf(m, rowmax[t + i * 1024]);
#pragma unroll
  for (int off = 32; off > 0; off >>= 1) m = fmaxf(m, __shfl_down(m, off, 64));
  __shared__ float s[16];
  if ((t & 63) == 0) s[t >> 6] = m;
  __syncthreads();
  if (t == 0) {
    float r = s[0];
#pragma unroll
    for (int i = 1; i < 16; ++i) r = fmaxf(r, s[i]);
    *gmax = r;
  }
}

// Pass 2 (r14's, proven): thread t reads its own ix4 at dword 4t, rescales
// by rowmax/gmax, overwrites its row span (per-thread RAW only -> race-free).
__global__ __launch_bounds__(256) void pass2(
    unsigned int* __restrict__ outw, const float* __restrict__ rowmax,
    const float* __restrict__ gmax, int* __restrict__ out) {
  const int row = blockIdx.x;
  const int t = threadIdx.x;
  const float c = rowmax[row] / *gmax;  // <= 1
  union { ix4 v; unsigned int w[4]; } u;
  u.v = *(const ix4*)(outw + (size_t)row * DD + 4 * t);
  ix4* orow = (ix4*)(out + (size_t)row * DD);
#pragma unroll
  for (int i = 0; i < 4; ++i) {
    const unsigned int w = u.w[i];
    ix4 q;
    q.x = min(max(__float2int_rn((float)((int)(w << 24) >> 24) * c), -128), 127);
    q.y = min(max(__float2int_rn((float)((int)(w << 16) >> 24) * c), -128), 127);
    q.z = min(max(__float2int_rn((float)((int)(w << 8) >> 24) * c), -128), 127);
    q.w = min(max(__float2int_rn((float)((int)w >> 24) * c), -128), 127);
    orow[t + i * 256] = q;  // i=0 exactly covers the dwords read
  }
}

// ---- Fallback (ws < 2 MB): recompute path ----
__global__ __launch_bounds__(256) void pass1_nb(
    const float* __restrict__ x, const float* __restrict__ res,
    const float* __restrict__ gamma, float* __restrict__ rstd,
    float* __restrict__ rowmax) {
  const int row = blockIdx.x;
  const int t = threadIdx.x;
  const fx4* x4 = (const fx4*)(x + (size_t)row * DD);
  const fx4* r4 = (const fx4*)(res + (size_t)row * DD);
  const fx4* g4 = (const fx4*)gamma;
  float ss = 0.f, mx = 0.f;
#pragma unroll
  for (int i = 0; i < 4; ++i) {
    const int idx = t + i * 256;
    fx4 y = x4[idx] + r4[idx];
    ss += y.x * y.x + y.y * y.y + y.z * y.z + y.w * y.w;
    fx4 p = y * g4[idx];
    mx = fmaxf(mx, fmaxf(fmaxf(fabsf(p.x), fabsf(p.y)),
                         fmaxf(fabsf(p.z), fabsf(p.w))));
  }
#pragma unroll
  for (int off = 32; off > 0; off >>= 1) {
    ss += __shfl_down(ss, off, 64);
    mx = fmaxf(mx, __shfl_down(mx, off, 64));
  }
  __shared__ float s_ss[4], s_mx[4];
  const int wave = t >> 6, lane = t & 63;
  if (lane == 0) { s_ss[wave] = ss; s_mx[wave] = mx; }
  __syncthreads();
  if (t == 0) {
    float tss = s_ss[0] + s_ss[1] + s_ss[2] + s_ss[3];
    float tmx = fmaxf(fmaxf(s_mx[0], s_mx[1]), fmaxf(s_mx[2], s_mx[3]));
    float rs = rsqrtf(tss * (1.0f / DD) + EPS);
    rstd[row] = rs;
    rowmax[row] = tmx * rs;
  }
}

__global__ __launch_bounds__(256) void pass2_nb(
    const float* __restrict__ x, const float* __restrict__ res,
    const float* __restrict__ gamma, const float* __restrict__ rstd,
    const float* __restrict__ gmax, int* __restrict__ out) {
  const int row = blockIdx.x;
  const int t = threadIdx.x;
  const float c = rstd[row] * (127.0f / *gmax);
  const fx4* x4 = (const fx4*)(x + (size_t)row * DD);
  const fx4* r4 = (const fx4*)(res + (size_t)row * DD);
  const fx4* g4 = (const fx4*)gamma;
  ix4* o4 = (ix4*)(out + (size_t)row * DD);
#pragma unroll
  for (int i = 0; i < 4; ++i) {
    const int idx = t + i * 256;
    fx4 xv = x4[idx], rv = r4[idx], gv = g4[idx];
    ix4 q;
    q.x = min(max(__float2int_rn((xv.x + rv.x) * gv.x * c), -128), 127);
    q.y = min(max(__float2int_rn((xv.y + rv.y) * gv.y * c), -128), 127);
    q.z = min(max(__float2int_rn((xv.z + rv.z) * gv.z * c), -128), 127);
    q.w = min(max(__float2int_rn((xv.w + rv.w) * gv.w * c), -128), 127);
    o4[idx] = q;
  }
}

extern "C" void kernel_launch(void* const* d_in, const int* in_sizes, int n_in,
                              void* d_out, int out_size, void* d_ws, size_t ws_size,
                              hipStream_t stream) {
  const float* x     = (const float*)d_in[0];
  const float* res   = (const float*)d_in[1];
  const float* gamma = (const float*)d_in[2];
  int* out = (int*)d_out;

  char* ws = (char*)d_ws;
  float* gmax   = (float*)ws;
  float* rowmax = (float*)(ws + 256);
  float* rstd   = (float*)(ws + 256 + 64 * 1024);  // fallback only

  if (ws_size >= (size_t)(2 << 20)) {
    unsigned int* outw = (unsigned int*)d_out;
    pass1_lds<<<NROWS, 256, 0, stream>>>(x, res, gamma, outw, rowmax);
    reduce_gmax<<<1, 1024, 0, stream>>>(rowmax, gmax);
    pass2<<<NROWS, 256, 0, stream>>>(outw, rowmax, gmax, out);
  } else {
    pass1_nb<<<NROWS, 256, 0, stream>>>(x, res, gamma, rstd, rowmax);
    reduce_gmax<<<1, 1024, 0, stream>>>(rowmax, gmax);
    pass2_nb<<<NROWS, 256, 0, stream>>>(x, res, gamma, rstd, gmax, out);
  }
}